// Round 4
// baseline (698.542 us; speedup 1.0000x reference)
//
#include <hip/hip_runtime.h>
#include <math.h>

#define B_    64
#define W_    128
#define N_    40
#define FIN   66
#define HID   100
#define NEWD  71
#define MSEQ  10
#define NBLK  256
#define NTHR  512   // 8 waves
#define E_    240

#define HXS   200   // hx row stride (f16 elems): >=192, 100 dwords -> 2-way banks (free)
#define CXS   136   // cx row stride (f16 elems): >=128, 68 dwords -> 2-way banks
#define CSS   101   // cs1 dword stride, [m][u] layout -> conflict-free for m<10
#define NGU   150   // gate A-frag units: 25 tiles * 6 kc
#define NU    178   // + decay units: 7 tiles * 4 kc

typedef float    f32x4 __attribute__((ext_vector_type(4)));
typedef _Float16 f16x8 __attribute__((ext_vector_type(8)));

__device__ __forceinline__ float sig_(float x) {
    return __builtin_amdgcn_rcpf(1.0f + __expf(-x));
}
__device__ __forceinline__ float tanh_(float x) {
    return fmaf(2.0f, __builtin_amdgcn_rcpf(1.0f + __expf(-2.0f * x)), -1.0f);
}

// ---------------------------------------------------------------------------
// Repack weights into f16 A-fragments for mfma_f32_16x16x32_f16.
// A-frag: lane l holds rows R=l&15, k=(l>>4)*8+e.
// GATE rows are interleaved: dest row R = 4*unit + gate  (gate: 0=f,1=i,2=o,3=ct)
//   -> source row = gate*100 + unit in Wall/Uall. k: [0,100)=Wall, [100,171)=Uall.
// DECAY rows natural: R = Wd row. Pads zero.
// ---------------------------------------------------------------------------
__global__ void repack_kernel(const float* __restrict__ Wall_w,
                              const float* __restrict__ Uall_w,
                              const float* __restrict__ Wd_w,
                              _Float16* __restrict__ Wfrag)
{
    int idx = blockIdx.x * 256 + threadIdx.x;
    if (idx >= NU * 64) return;
    int u = idx >> 6, l = idx & 63;
    f16x8 v;
    #pragma unroll
    for (int e = 0; e < 8; ++e) {
        float wv = 0.0f;
        int k = ((l >> 4) << 3) + e;
        if (u < NGU) {
            int T = u / 6, j = u % 6;
            int R = T * 16 + (l & 15);
            int src = (R & 3) * 100 + (R >> 2);   // gate*100 + unit
            k += j * 32;
            if (k < 100)      wv = Wall_w[src * HID + k];
            else if (k < 171) wv = Uall_w[src * NEWD + (k - 100)];
        } else {
            int du = u - NGU;
            int D = du >> 2, j = du & 3;
            int R = D * 16 + (l & 15);
            k += j * 32;
            if (R < 100 && k < 100) wv = Wd_w[R * HID + k];
        }
        v[e] = (_Float16)wv;
    }
    *(f16x8*)(Wfrag + (size_t)idx * 8) = v;
}

// ---------------------------------------------------------------------------
// LSTM: 256 blocks x 512 threads (8 waves). f16 MFMA, in-register gate update.
// Slots per wave: wv 0-5: 4 gate tiles {wv,wv+6,wv+12,wv+18}; wv 6: gate tile
// 24 + decay {0,1,2}; wv 7: decay {3,4,5,6}.
// Per step: P1 [MFMA(+bias-in-acc) ; gate: sig->g ; decay: tanh->cs1_s ; issue
// X prefetch] | bar | P2 [gate lanes: read cs1, fp32 c/h update, write h/c f16
// to B-buffers ; staging writes xe(w+1), ts(w+1)] | bar
// ---------------------------------------------------------------------------
__global__ __launch_bounds__(NTHR, 2)
void lstm_kernel(const float* __restrict__ X, const float* __restrict__ ts,
                 const float* __restrict__ emb_pos, const float* __restrict__ emb_team,
                 const _Float16* __restrict__ Wfrag,
                 const float* __restrict__ Wall_b, const float* __restrict__ Uall_b,
                 const float* __restrict__ Wd_b,
                 const float* __restrict__ lin_w, const float* __restrict__ lin_b,
                 float* __restrict__ nodes)
{
    __shared__ __align__(16) _Float16 hx[16 * HXS];  // [m][k] k<100:h, 100..170:xe
    __shared__ __align__(16) _Float16 cx[16 * CXS];  // [m][k] k<100:c
    __shared__ float cs1_s[16 * CSS];                // [m][u]
    __shared__ float bias_s[400];                    // Wall_b+Uall_b
    __shared__ float bd_s[HID];
    __shared__ float ts_s[2][16];

    const int t = threadIdx.x, l = t & 63, wv = t >> 6;
    const int uoff = l >> 4, m = l & 15;
    const int r0 = blockIdx.x * MSEQ;

    // ---- init LDS ----
    for (int i = t; i < 16 * HXS; i += NTHR) hx[i] = (_Float16)0.0f;
    for (int i = t; i < 16 * CXS; i += NTHR) cx[i] = (_Float16)0.0f;
    for (int i = t; i < 400; i += NTHR) bias_s[i] = Wall_b[i] + Uall_b[i];
    if (t < HID) bd_s[t] = Wd_b[t];
    if (t < 32) ((float*)ts_s)[t] = 0.0f;

    // ---- slots ----
    const int nG = (wv < 6) ? 4 : (wv == 6 ? 1 : 0);
    const int nD = (wv == 6) ? 3 : (wv == 7 ? 4 : 0);
    int Ts[4], Ds[4], Us[4];
    #pragma unroll
    for (int i = 0; i < 4; ++i) {
        Ts[i] = (wv < 6) ? (wv + 6 * i) : 24;
        Ds[i] = (wv == 6) ? (i - 1) : (i + 3);
        Us[i] = Ts[i] * 4 + uoff;
    }

    // ---- persistent A-frags ----
    f16x8 af[4][6];
    f16x8 afd[4][4];
    #pragma unroll
    for (int i = 0; i < 4; ++i) {
        if (i < nG) {
            #pragma unroll
            for (int j = 0; j < 6; ++j)
                af[i][j] = *(const f16x8*)(Wfrag + ((size_t)(Ts[i] * 6 + j) * 64 + l) * 8);
        }
        if (i >= nG && i < nG + nD) {
            #pragma unroll
            for (int j = 0; j < 4; ++j)
                afd[i][j] = *(const f16x8*)(Wfrag + ((size_t)(NGU + Ds[i] * 4 + j) * 64 + l) * 8);
        }
    }
    float creg[4] = {0.f, 0.f, 0.f, 0.f};

    // ---- staging roles ----
    const float* xld = nullptr; int xm = 0, xk = 0;
    const float* xcat = nullptr; int me = 0;
    const float* tsp = nullptr; int mt = 0;
    if (t < 320) {
        xm = t >> 5; int p = t & 31;
        int r = r0 + xm, b = r / N_, n = r % N_;
        xld = X + ((size_t)b * W_ * N_ + n) * FIN + 2 * p;
        xk = 100 + 2 * p;
    } else if (t < 330) {
        me = t - 320;
        int r = r0 + me, b = r / N_, n = r % N_;
        xcat = X + ((size_t)b * W_ * N_ + n) * FIN;
    } else if (t < 340) {
        mt = t - 330;
        int r = r0 + mt, b = r / N_, n = r % N_;
        tsp = ts + (size_t)b * W_ * N_ + n;
    }

    // ---- prologue: stage xe(0), ts(0) ----
    if (xld) {
        float2 x0 = *(const float2*)xld;
        hx[xm * HXS + xk]     = (_Float16)x0.x;
        hx[xm * HXS + xk + 1] = (_Float16)x0.y;
    }
    if (xcat) {
        float c0f = xcat[64], c1f = xcat[65];
        int ip = (int)c0f, itm = (int)c1f;
        int sp = ip > 0 ? ip - 1 : 0;   float fp  = ip > 0 ? 1.f : 0.f;
        int st = itm > 0 ? itm - 1 : 0; float ft_ = itm > 0 ? 1.f : 0.f;
        #pragma unroll
        for (int q = 0; q < 4; ++q) hx[me * HXS + 164 + q] = (_Float16)(emb_pos[sp * 4 + q] * fp);
        #pragma unroll
        for (int q = 0; q < 3; ++q) hx[me * HXS + 168 + q] = (_Float16)(emb_team[st * 3 + q] * ft_);
    }
    if (tsp) ts_s[0][mt] = tsp[0];
    __syncthreads();

    const int bah = m * HXS + (uoff << 3);
    const int bac = m * CXS + (uoff << 3);

    // ---- main loop ----
    for (int w = 0; w < W_; ++w) {
        const int cur = w & 1, nxt = cur ^ 1;
        const bool pf = (w + 1 < W_);

        // prefetch issue (consumed in P2)
        float2 xv = {0.f, 0.f}; float c0f = 0.f, c1f = 0.f, tv = 0.f;
        if (pf) {
            const size_t off = (size_t)(w + 1) * (N_ * FIN);
            if (xld)  xv  = *(const float2*)(xld + off);
            if (xcat) { c0f = xcat[off + 64]; c1f = xcat[off + 65]; }
            if (tsp)  tv  = tsp[(size_t)(w + 1) * N_];
        }

        // ===== P1: MFMA (bias pre-loaded into acc) =====
        f32x4 acc[4];
        #pragma unroll
        for (int i = 0; i < 4; ++i) {
            if (i < nG) {
                acc[i][0] = bias_s[Us[i]];
                acc[i][1] = bias_s[100 + Us[i]];
                acc[i][2] = bias_s[200 + Us[i]];
                acc[i][3] = bias_s[300 + Us[i]];
            } else if (i < nG + nD) {
                #pragma unroll
                for (int q = 0; q < 4; ++q) {
                    int r = Ds[i] * 16 + uoff * 4 + q;
                    acc[i][q] = (r < HID) ? bd_s[r] : 0.f;
                }
            }
        }
        if (nG > 0) {
            #pragma unroll
            for (int j = 0; j < 6; ++j) {
                f16x8 bb = *(const f16x8*)&hx[bah + j * 32];
                #pragma unroll
                for (int i = 0; i < 4; ++i)
                    if (i < nG)
                        acc[i] = __builtin_amdgcn_mfma_f32_16x16x32_f16(af[i][j], bb, acc[i], 0, 0, 0);
            }
        }
        if (nD > 0) {
            #pragma unroll
            for (int j = 0; j < 4; ++j) {
                f16x8 bb = *(const f16x8*)&cx[bac + j * 32];
                #pragma unroll
                for (int i = 0; i < 4; ++i)
                    if (i >= nG && i < nG + nD)
                        acc[i] = __builtin_amdgcn_mfma_f32_16x16x32_f16(afd[i][j], bb, acc[i], 0, 0, 0);
            }
        }
        // gate: sigmoid in-register; decay: tanh -> cs1_s
        float g[4][4];
        #pragma unroll
        for (int i = 0; i < 4; ++i) {
            if (i < nG) {
                #pragma unroll
                for (int q = 0; q < 4; ++q) g[i][q] = sig_(acc[i][q]);
            } else if (i < nG + nD) {
                #pragma unroll
                for (int q = 0; q < 4; ++q) {
                    int r = Ds[i] * 16 + uoff * 4 + q;
                    if (r < HID) cs1_s[m * CSS + r] = tanh_(acc[i][q]);
                }
            }
        }
        __syncthreads();

        // ===== P2: in-register state update =====
        if (nG > 0) {
            const float tsv = ts_s[cur][m];
            #pragma unroll
            for (int i = 0; i < 4; ++i) {
                if (i < nG) {
                    float cs1v = cs1_s[m * CSS + Us[i]];
                    float cadj = fmaf(cs1v, tsv - 1.0f, creg[i]);
                    float cn = g[i][0] * cadj + g[i][1] * g[i][3];
                    creg[i] = cn;
                    float hn = g[i][2] * tanh_(cn);
                    if (m < MSEQ) {
                        hx[m * HXS + Us[i]] = (_Float16)hn;
                        cx[m * CXS + Us[i]] = (_Float16)cn;
                    }
                }
            }
        }
        if (pf) {
            if (xld) {
                hx[xm * HXS + xk]     = (_Float16)xv.x;
                hx[xm * HXS + xk + 1] = (_Float16)xv.y;
            }
            if (xcat) {
                int ip = (int)c0f, itm = (int)c1f;
                int sp = ip > 0 ? ip - 1 : 0;   float fp  = ip > 0 ? 1.f : 0.f;
                int st = itm > 0 ? itm - 1 : 0; float ft_ = itm > 0 ? 1.f : 0.f;
                #pragma unroll
                for (int q = 0; q < 4; ++q) hx[me * HXS + 164 + q] = (_Float16)(emb_pos[sp * 4 + q] * fp);
                #pragma unroll
                for (int q = 0; q < 3; ++q) hx[me * HXS + 168 + q] = (_Float16)(emb_team[st * 3 + q] * ft_);
            }
            if (tsp) ts_s[nxt][mt] = tv;
        }
        __syncthreads();
    }

    // ---- lin head: nodes = relu(h @ lin_w^T + lin_b), h read back from hx ----
    for (int idx = t; idx < HID * MSEQ; idx += NTHR) {
        const int i = idx / MSEQ, mm = idx % MSEQ;
        const float* lr = lin_w + (size_t)i * HID;
        float acc2 = lin_b[i];
        for (int k = 0; k < HID; ++k)
            acc2 = fmaf(lr[k], (float)hx[mm * HXS + k], acc2);
        nodes[(size_t)(r0 + mm) * HID + i] = fmaxf(acc2, 0.0f);
    }
}

// ---------------------------------------------------------------------------
// Kernel B: per-batch GraphSAGE x2 + output head, all in LDS. (unchanged)
// ---------------------------------------------------------------------------
__global__ __launch_bounds__(256, 1)
void sage_kernel(const float* __restrict__ nodes, const int* __restrict__ edge,
                 const float* __restrict__ s1l, const float* __restrict__ s1lb,
                 const float* __restrict__ s1r,
                 const float* __restrict__ s2l, const float* __restrict__ s2lb,
                 const float* __restrict__ s2r,
                 const float* __restrict__ ow,  const float* __restrict__ ob,
                 float* __restrict__ out)
{
    __shared__ float nd[N_ * HID];
    __shared__ float agg[N_ * HID];
    __shared__ float g1[N_ * 64];
    __shared__ float agg2[N_ * 64];
    __shared__ float g2[N_ * 32];
    __shared__ float deg[N_];
    __shared__ float invdeg[N_];

    const int t = threadIdx.x;
    const int b = blockIdx.x;
    const int* esrc = edge;
    const int* edst = edge + E_;

    for (int i = t; i < N_ * HID; i += 256) {
        nd[i]  = nodes[(size_t)b * N_ * HID + i];
        agg[i] = 0.0f;
    }
    for (int i = t; i < N_; i += 256) deg[i] = 0.0f;
    __syncthreads();

    if (t < E_) atomicAdd(&deg[edst[t]], 1.0f);
    for (int i = t; i < E_ * HID; i += 256) {
        int e = i / HID, k = i % HID;
        atomicAdd(&agg[edst[e] * HID + k], nd[esrc[e] * HID + k]);
    }
    __syncthreads();
    for (int i = t; i < N_; i += 256) invdeg[i] = 1.0f / fmaxf(deg[i], 1.0f);
    __syncthreads();

    for (int idx = t; idx < N_ * 64; idx += 256) {
        int n = idx / 64, i = idx % 64;
        const float* lr = s1l + (size_t)i * HID;
        const float* rr = s1r + (size_t)i * HID;
        float id = invdeg[n];
        float acc = s1lb[i];
        for (int k = 0; k < HID; ++k)
            acc += lr[k] * (agg[n * HID + k] * id) + rr[k] * nd[n * HID + k];
        g1[idx] = fmaxf(acc, 0.0f);
    }
    __syncthreads();
    for (int i = t; i < N_ * 64; i += 256) agg2[i] = 0.0f;
    __syncthreads();
    for (int i = t; i < E_ * 64; i += 256) {
        int e = i / 64, k = i % 64;
        atomicAdd(&agg2[edst[e] * 64 + k], g1[esrc[e] * 64 + k]);
    }
    __syncthreads();

    for (int idx = t; idx < N_ * 32; idx += 256) {
        int n = idx / 32, i = idx % 32;
        const float* lr = s2l + (size_t)i * 64;
        const float* rr = s2r + (size_t)i * 64;
        float id = invdeg[n];
        float acc = s2lb[i];
        for (int k = 0; k < 64; ++k)
            acc += lr[k] * (agg2[n * 64 + k] * id) + rr[k] * g1[n * 64 + k];
        g2[idx] = fmaxf(acc, 0.0f);
    }
    __syncthreads();

    for (int idx = t; idx < N_ * 2; idx += 256) {
        int n = idx / 2, c = idx % 2;
        const float* wr = ow + (size_t)c * 32;
        float acc = ob[c];
        for (int k = 0; k < 32; ++k) acc += wr[k] * g2[n * 32 + k];
        out[((size_t)b * N_ + n) * 2 + c] = fmaxf(acc, 0.0f);
    }
}

extern "C" void kernel_launch(void* const* d_in, const int* in_sizes, int n_in,
                              void* d_out, int out_size, void* d_ws, size_t ws_size,
                              hipStream_t stream) {
    const float* X        = (const float*)d_in[0];
    const float* ts       = (const float*)d_in[1];
    const int*   edge     = (const int*)  d_in[2];
    const float* emb_pos  = (const float*)d_in[3];
    const float* emb_team = (const float*)d_in[4];
    const float* Wall_w   = (const float*)d_in[5];
    const float* Wall_b   = (const float*)d_in[6];
    const float* Uall_w   = (const float*)d_in[7];
    const float* Uall_b   = (const float*)d_in[8];
    const float* Wd_w     = (const float*)d_in[9];
    const float* Wd_b     = (const float*)d_in[10];
    const float* lin_w    = (const float*)d_in[11];
    const float* lin_b    = (const float*)d_in[12];
    const float* s1l      = (const float*)d_in[13];
    const float* s1lb     = (const float*)d_in[14];
    const float* s1r      = (const float*)d_in[15];
    const float* s2l      = (const float*)d_in[16];
    const float* s2lb     = (const float*)d_in[17];
    const float* s2r      = (const float*)d_in[18];
    const float* ow       = (const float*)d_in[19];
    const float* ob       = (const float*)d_in[20];

    float*     nodes = (float*)d_ws;                              // 1,024,000 B
    _Float16*  Wfrag = (_Float16*)((char*)d_ws + 1024000);        // 178*64*8*2 = 182,272 B

    repack_kernel<<<(NU * 64 + 255) / 256, 256, 0, stream>>>(Wall_w, Uall_w, Wd_w, Wfrag);

    lstm_kernel<<<NBLK, NTHR, 0, stream>>>(X, ts, emb_pos, emb_team, Wfrag,
                                           Wall_b, Uall_b, Wd_b,
                                           lin_w, lin_b, nodes);
    sage_kernel<<<B_, 256, 0, stream>>>(nodes, edge, s1l, s1lb, s1r,
                                        s2l, s2lb, s2r, ow, ob, (float*)d_out);
}

// Round 5
// 415.480 us; speedup vs baseline: 1.6813x; 1.6813x over previous
//
#include <hip/hip_runtime.h>
#include <math.h>

#define B_    64
#define W_    128
#define N_    40
#define FIN   66
#define HID   100
#define NEWD  71
#define MSEQ  10
#define NBLK  256
#define NTHR  1024  // 16 waves
#define E_    240

#define NGU   150   // gate A-frag units: 25 tiles * 6 kc
#define NU    178   // + decay units: 7 tiles * 4 kc

// LDS row offsets with +8-elem bump every 8 rows (kills m/m+8 bank aliasing)
#define ROWH(m) ((m)*200 + (((m)>>3)<<3))
#define ROWC(m) ((m)*136 + (((m)>>3)<<3))
#define HXSZ  (15*200 + 8 + 200)   // 3208 f16
#define CXSZ  (15*136 + 8 + 136)   // 2184 f16
#define CSS   100                  // cs1 dword stride

typedef float    f32x4 __attribute__((ext_vector_type(4)));
typedef _Float16 f16x4 __attribute__((ext_vector_type(4)));
typedef _Float16 f16x8 __attribute__((ext_vector_type(8)));

__device__ __forceinline__ float sig_(float x) {
    return __builtin_amdgcn_rcpf(1.0f + __expf(-x));
}
__device__ __forceinline__ float tanh_(float x) {
    return fmaf(2.0f, __builtin_amdgcn_rcpf(1.0f + __expf(-2.0f * x)), -1.0f);
}

// ---------------------------------------------------------------------------
// Repack weights into f16 A-fragments for mfma_f32_16x16x32_f16 (unchanged
// from round 4; validated absmax 2.44e-4).
// GATE rows interleaved: dest row R = 4*unit + gate -> src row gate*100+unit.
// DECAY rows natural. Pads zero.
// ---------------------------------------------------------------------------
__global__ void repack_kernel(const float* __restrict__ Wall_w,
                              const float* __restrict__ Uall_w,
                              const float* __restrict__ Wd_w,
                              _Float16* __restrict__ Wfrag)
{
    int idx = blockIdx.x * 256 + threadIdx.x;
    if (idx >= NU * 64) return;
    int u = idx >> 6, l = idx & 63;
    f16x8 v;
    #pragma unroll
    for (int e = 0; e < 8; ++e) {
        float wv = 0.0f;
        int k = ((l >> 4) << 3) + e;
        if (u < NGU) {
            int T = u / 6, j = u % 6;
            int R = T * 16 + (l & 15);
            int src = (R & 3) * 100 + (R >> 2);
            k += j * 32;
            if (k < 100)      wv = Wall_w[src * HID + k];
            else if (k < 171) wv = Uall_w[src * NEWD + (k - 100)];
        } else {
            int du = u - NGU;
            int D = du >> 2, j = du & 3;
            int R = D * 16 + (l & 15);
            k += j * 32;
            if (R < 100 && k < 100) wv = Wd_w[R * HID + k];
        }
        v[e] = (_Float16)wv;
    }
    *(f16x8*)(Wfrag + (size_t)idx * 8) = v;
}

// ---------------------------------------------------------------------------
// LSTM: 256 blocks x 1024 threads (16 waves, 4/SIMD). f16 MFMA, 2 slots/wave.
// Slots: wv<12: gates {2wv, 2wv+1}; wv==12: gate 24 + decay 0; wv>=13: decay
// {2(wv-13)+1, 2(wv-13)+2}. Lane (tile,uoff,m): owns unit u=4T+uoff, seq m;
// acc[q] = gate q preact (gate-interleaved A rows).
// Staging (X/emb/ts) on decay waves (threads >= 832), prefetched 1 full step.
// Per step: P1 [B-reads + MFMA + sig/tanh + cs1 write] bar
//           P2 [in-reg c/h update + xe(w+1) LDS write + issue loads(w+2)] bar
// ---------------------------------------------------------------------------
__global__ __launch_bounds__(NTHR, 4)
void lstm_kernel(const float* __restrict__ X, const float* __restrict__ ts,
                 const float* __restrict__ emb_pos, const float* __restrict__ emb_team,
                 const _Float16* __restrict__ Wfrag,
                 const float* __restrict__ Wall_b, const float* __restrict__ Uall_b,
                 const float* __restrict__ Wd_b,
                 const float* __restrict__ lin_w, const float* __restrict__ lin_b,
                 float* __restrict__ nodes)
{
    __shared__ __align__(16) _Float16 hx[HXSZ];   // [m][k] k<100:h, 100..170:xe
    __shared__ __align__(16) _Float16 cx[CXSZ];   // [m][k] k<100:c
    __shared__ __align__(16) float cs1_s[16 * CSS];
    __shared__ float ts_s[2][16];

    const int t = threadIdx.x, l = t & 63, wv = t >> 6;
    const int uoff = l >> 4, m = l & 15;
    const int r0 = blockIdx.x * MSEQ;

    for (int i = t; i < HXSZ; i += NTHR) hx[i] = (_Float16)0.0f;
    for (int i = t; i < CXSZ; i += NTHR) cx[i] = (_Float16)0.0f;
    if (t < 32) ((float*)ts_s)[t] = 0.0f;

    // ---- slots (wave-uniform) ----
    int typA, tA, typB, tB;   // 0 = gate, 1 = decay
    if (wv < 12)       { typA = 0; tA = 2 * wv;            typB = 0; tB = 2 * wv + 1; }
    else if (wv == 12) { typA = 0; tA = 24;                typB = 1; tB = 0; }
    else               { typA = 1; tA = 2 * (wv - 13) + 1; typB = 1; tB = 2 * (wv - 13) + 2; }

    // ---- A-fragments (union: slot A/B each 6 regs max) ----
    f16x8 afA[6], afB[6];
    {
        int baseA = typA ? (NGU + tA * 4) : (tA * 6);
        int nA = typA ? 4 : 6;
        for (int j = 0; j < nA; ++j)
            afA[j] = *(const f16x8*)(Wfrag + ((size_t)(baseA + j) * 64 + l) * 8);
        int baseB = typB ? (NGU + tB * 4) : (tB * 6);
        int nB = typB ? 4 : 6;
        for (int j = 0; j < nB; ++j)
            afB[j] = *(const f16x8*)(Wfrag + ((size_t)(baseB + j) * 64 + l) * 8);
    }

    // ---- biases (hoisted to registers) ----
    const int uA = 4 * tA + uoff, uB = 4 * tB + uoff;
    float biA[4], biB[4];
    #pragma unroll
    for (int q = 0; q < 4; ++q) {
        if (typA == 0) biA[q] = Wall_b[q * 100 + uA] + Uall_b[q * 100 + uA];
        else { int r = tA * 16 + 4 * uoff + q; biA[q] = (r < HID) ? Wd_b[r] : 0.f; }
        if (typB == 0) biB[q] = Wall_b[q * 100 + uB] + Uall_b[q * 100 + uB];
        else { int r = tB * 16 + 4 * uoff + q; biB[q] = (r < HID) ? Wd_b[r] : 0.f; }
    }
    float cregA = 0.f, cregB = 0.f;

    // ---- staging roles (decay waves: t >= 832) ----
    const float* xld = nullptr; int xm = 0, xp = 0;
    const float* xcat = nullptr; int me = 0;
    const float* tsp = nullptr; int mt = 0;
    {
        int s = t - 832;
        if (s >= 0 && s < 160) {
            xm = s >> 4; xp = s & 15;
            int r = r0 + xm, b = r / N_, n = r % N_;
            xld = X + ((size_t)b * W_ * N_ + n) * FIN + 4 * xp;
        } else if (s >= 160 && s < 170) {
            me = s - 160;
            int r = r0 + me, b = r / N_, n = r % N_;
            xcat = X + ((size_t)b * W_ * N_ + n) * FIN;
        } else if (s >= 170 && s < 180) {
            mt = s - 170;
            int r = r0 + mt, b = r / N_, n = r % N_;
            tsp = ts + (size_t)b * W_ * N_ + n;
        }
    }

    // ---- prologue: stage step 0 ----
    if (xld) {
        float2 a = *(const float2*)xld;
        float2 b2 = *(const float2*)(xld + 2);
        f16x4 v = {(_Float16)a.x, (_Float16)a.y, (_Float16)b2.x, (_Float16)b2.y};
        *(f16x4*)&hx[ROWH(xm) + 100 + 4 * xp] = v;
    }
    if (xcat) {
        float c0f = xcat[64], c1f = xcat[65];
        int ip = (int)c0f, itm = (int)c1f;
        int sp = ip > 0 ? ip - 1 : 0;   float fp  = ip > 0 ? 1.f : 0.f;
        int st = itm > 0 ? itm - 1 : 0; float ft_ = itm > 0 ? 1.f : 0.f;
        #pragma unroll
        for (int q = 0; q < 4; ++q) hx[ROWH(me) + 164 + q] = (_Float16)(emb_pos[sp * 4 + q] * fp);
        #pragma unroll
        for (int q = 0; q < 3; ++q) hx[ROWH(me) + 168 + q] = (_Float16)(emb_team[st * 3 + q] * ft_);
    }
    if (tsp) ts_s[0][mt] = tsp[0];

    // ---- pre-load regs for step 1 ----
    float2 pa = {0.f, 0.f}, pb = {0.f, 0.f};
    float pc0 = 0.f, pc1 = 0.f, ptv = 0.f;
    {
        const size_t off1 = (size_t)N_ * FIN;
        if (xld)  { pa = *(const float2*)(xld + off1); pb = *(const float2*)(xld + off1 + 2); }
        if (xcat) { pc0 = xcat[off1 + 64]; pc1 = xcat[off1 + 65]; }
        if (tsp)  ptv = tsp[(size_t)N_];
    }
    __syncthreads();

    const int rowh = ROWH(m), rowc = ROWC(m);
    const int bko = uoff << 3;

    // ---- main loop ----
    for (int w = 0; w < W_; ++w) {
        // ===== P1: MFMA =====
        f32x4 accA = {biA[0], biA[1], biA[2], biA[3]};
        f32x4 accB = {biB[0], biB[1], biB[2], biB[3]};

        if (typA == 0) {                    // slot A gate (=> waves 0..12)
            f16x8 bbh[6];
            #pragma unroll
            for (int j = 0; j < 6; ++j) bbh[j] = *(const f16x8*)&hx[rowh + bko + j * 32];
            #pragma unroll
            for (int j = 0; j < 6; ++j) {
                accA = __builtin_amdgcn_mfma_f32_16x16x32_f16(afA[j], bbh[j], accA, 0, 0, 0);
                if (typB == 0)
                    accB = __builtin_amdgcn_mfma_f32_16x16x32_f16(afB[j], bbh[j], accB, 0, 0, 0);
            }
            if (typB == 1) {                // wave 12: decay slot B
                #pragma unroll
                for (int j = 0; j < 4; ++j) {
                    f16x8 bc = *(const f16x8*)&cx[rowc + bko + j * 32];
                    accB = __builtin_amdgcn_mfma_f32_16x16x32_f16(afB[j], bc, accB, 0, 0, 0);
                }
            }
        } else {                            // waves 13..15: both decay
            #pragma unroll
            for (int j = 0; j < 4; ++j) {
                f16x8 bc = *(const f16x8*)&cx[rowc + bko + j * 32];
                accA = __builtin_amdgcn_mfma_f32_16x16x32_f16(afA[j], bc, accA, 0, 0, 0);
                accB = __builtin_amdgcn_mfma_f32_16x16x32_f16(afB[j], bc, accB, 0, 0, 0);
            }
        }

        // gate: sigmoid in-register; decay: tanh -> cs1_s (b128)
        float gA[4], gB[4];
        if (typA == 0) {
            #pragma unroll
            for (int q = 0; q < 4; ++q) gA[q] = sig_(accA[q]);
        } else {
            int cb = tA * 16 + 4 * uoff;
            if (cb < HID) {
                f32x4 v = {tanh_(accA[0]), tanh_(accA[1]), tanh_(accA[2]), tanh_(accA[3])};
                *(f32x4*)&cs1_s[m * CSS + cb] = v;
            }
        }
        if (typB == 0) {
            #pragma unroll
            for (int q = 0; q < 4; ++q) gB[q] = sig_(accB[q]);
        } else {
            int cb = tB * 16 + 4 * uoff;
            if (cb < HID) {
                f32x4 v = {tanh_(accB[0]), tanh_(accB[1]), tanh_(accB[2]), tanh_(accB[3])};
                *(f32x4*)&cs1_s[m * CSS + cb] = v;
            }
        }
        __syncthreads();

        // ===== P2: in-register state update + staging =====
        const int cur = w & 1, nxt = cur ^ 1;
        if (typA == 0 && m < MSEQ) {
            const float tsv = ts_s[cur][m];
            {
                float cs1v = cs1_s[m * CSS + uA];
                float cadj = fmaf(cs1v, tsv - 1.0f, cregA);
                float cn = gA[0] * cadj + gA[1] * gA[3];
                cregA = cn;
                hx[rowh + uA] = (_Float16)(gA[2] * tanh_(cn));
                cx[rowc + uA] = (_Float16)cn;
            }
            if (typB == 0) {
                float cs1v = cs1_s[m * CSS + uB];
                float cadj = fmaf(cs1v, tsv - 1.0f, cregB);
                float cn = gB[0] * cadj + gB[1] * gB[3];
                cregB = cn;
                hx[rowh + uB] = (_Float16)(gB[2] * tanh_(cn));
                cx[rowc + uB] = (_Float16)cn;
            }
        }
        if (w + 1 < W_) {
            if (xld) {
                f16x4 v = {(_Float16)pa.x, (_Float16)pa.y, (_Float16)pb.x, (_Float16)pb.y};
                *(f16x4*)&hx[ROWH(xm) + 100 + 4 * xp] = v;
            }
            if (xcat) {
                int ip = (int)pc0, itm = (int)pc1;
                int sp = ip > 0 ? ip - 1 : 0;   float fp  = ip > 0 ? 1.f : 0.f;
                int st = itm > 0 ? itm - 1 : 0; float ft_ = itm > 0 ? 1.f : 0.f;
                #pragma unroll
                for (int q = 0; q < 4; ++q) hx[ROWH(me) + 164 + q] = (_Float16)(emb_pos[sp * 4 + q] * fp);
                #pragma unroll
                for (int q = 0; q < 3; ++q) hx[ROWH(me) + 168 + q] = (_Float16)(emb_team[st * 3 + q] * ft_);
            }
            if (tsp) ts_s[nxt][mt] = ptv;
            if (w + 2 < W_) {
                const size_t off = (size_t)(w + 2) * (N_ * FIN);
                if (xld)  { pa = *(const float2*)(xld + off); pb = *(const float2*)(xld + off + 2); }
                if (xcat) { pc0 = xcat[off + 64]; pc1 = xcat[off + 65]; }
                if (tsp)  ptv = tsp[(size_t)(w + 2) * N_];
            }
        }
        __syncthreads();
    }

    // ---- lin head: nodes = relu(h @ lin_w^T + lin_b) ----
    if (t < HID * MSEQ) {
        const int i = t / MSEQ, mm = t % MSEQ;
        const float* lr = lin_w + (size_t)i * HID;
        float acc2 = lin_b[i];
        for (int k = 0; k < HID; ++k)
            acc2 = fmaf(lr[k], (float)hx[ROWH(mm) + k], acc2);
        nodes[(size_t)(r0 + mm) * HID + i] = fmaxf(acc2, 0.0f);
    }
}

// ---------------------------------------------------------------------------
// Kernel B: per-batch GraphSAGE x2 + output head, all in LDS. (unchanged)
// ---------------------------------------------------------------------------
__global__ __launch_bounds__(256, 1)
void sage_kernel(const float* __restrict__ nodes, const int* __restrict__ edge,
                 const float* __restrict__ s1l, const float* __restrict__ s1lb,
                 const float* __restrict__ s1r,
                 const float* __restrict__ s2l, const float* __restrict__ s2lb,
                 const float* __restrict__ s2r,
                 const float* __restrict__ ow,  const float* __restrict__ ob,
                 float* __restrict__ out)
{
    __shared__ float nd[N_ * HID];
    __shared__ float agg[N_ * HID];
    __shared__ float g1[N_ * 64];
    __shared__ float agg2[N_ * 64];
    __shared__ float g2[N_ * 32];
    __shared__ float deg[N_];
    __shared__ float invdeg[N_];

    const int t = threadIdx.x;
    const int b = blockIdx.x;
    const int* esrc = edge;
    const int* edst = edge + E_;

    for (int i = t; i < N_ * HID; i += 256) {
        nd[i]  = nodes[(size_t)b * N_ * HID + i];
        agg[i] = 0.0f;
    }
    for (int i = t; i < N_; i += 256) deg[i] = 0.0f;
    __syncthreads();

    if (t < E_) atomicAdd(&deg[edst[t]], 1.0f);
    for (int i = t; i < E_ * HID; i += 256) {
        int e = i / HID, k = i % HID;
        atomicAdd(&agg[edst[e] * HID + k], nd[esrc[e] * HID + k]);
    }
    __syncthreads();
    for (int i = t; i < N_; i += 256) invdeg[i] = 1.0f / fmaxf(deg[i], 1.0f);
    __syncthreads();

    for (int idx = t; idx < N_ * 64; idx += 256) {
        int n = idx / 64, i = idx % 64;
        const float* lr = s1l + (size_t)i * HID;
        const float* rr = s1r + (size_t)i * HID;
        float id = invdeg[n];
        float acc = s1lb[i];
        for (int k = 0; k < HID; ++k)
            acc += lr[k] * (agg[n * HID + k] * id) + rr[k] * nd[n * HID + k];
        g1[idx] = fmaxf(acc, 0.0f);
    }
    __syncthreads();
    for (int i = t; i < N_ * 64; i += 256) agg2[i] = 0.0f;
    __syncthreads();
    for (int i = t; i < E_ * 64; i += 256) {
        int e = i / 64, k = i % 64;
        atomicAdd(&agg2[edst[e] * 64 + k], g1[esrc[e] * 64 + k]);
    }
    __syncthreads();

    for (int idx = t; idx < N_ * 32; idx += 256) {
        int n = idx / 32, i = idx % 32;
        const float* lr = s2l + (size_t)i * 64;
        const float* rr = s2r + (size_t)i * 64;
        float id = invdeg[n];
        float acc = s2lb[i];
        for (int k = 0; k < 64; ++k)
            acc += lr[k] * (agg2[n * 64 + k] * id) + rr[k] * g1[n * 64 + k];
        g2[idx] = fmaxf(acc, 0.0f);
    }
    __syncthreads();

    for (int idx = t; idx < N_ * 2; idx += 256) {
        int n = idx / 2, c = idx % 2;
        const float* wr = ow + (size_t)c * 32;
        float acc = ob[c];
        for (int k = 0; k < 32; ++k) acc += wr[k] * g2[n * 32 + k];
        out[((size_t)b * N_ + n) * 2 + c] = fmaxf(acc, 0.0f);
    }
}

extern "C" void kernel_launch(void* const* d_in, const int* in_sizes, int n_in,
                              void* d_out, int out_size, void* d_ws, size_t ws_size,
                              hipStream_t stream) {
    const float* X        = (const float*)d_in[0];
    const float* ts       = (const float*)d_in[1];
    const int*   edge     = (const int*)  d_in[2];
    const float* emb_pos  = (const float*)d_in[3];
    const float* emb_team = (const float*)d_in[4];
    const float* Wall_w   = (const float*)d_in[5];
    const float* Wall_b   = (const float*)d_in[6];
    const float* Uall_w   = (const float*)d_in[7];
    const float* Uall_b   = (const float*)d_in[8];
    const float* Wd_w     = (const float*)d_in[9];
    const float* Wd_b     = (const float*)d_in[10];
    const float* lin_w    = (const float*)d_in[11];
    const float* lin_b    = (const float*)d_in[12];
    const float* s1l      = (const float*)d_in[13];
    const float* s1lb     = (const float*)d_in[14];
    const float* s1r      = (const float*)d_in[15];
    const float* s2l      = (const float*)d_in[16];
    const float* s2lb     = (const float*)d_in[17];
    const float* s2r      = (const float*)d_in[18];
    const float* ow       = (const float*)d_in[19];
    const float* ob       = (const float*)d_in[20];

    float*     nodes = (float*)d_ws;                              // 1,024,000 B
    _Float16*  Wfrag = (_Float16*)((char*)d_ws + 1024000);        // 182,272 B

    repack_kernel<<<(NU * 64 + 255) / 256, 256, 0, stream>>>(Wall_w, Uall_w, Wd_w, Wfrag);

    lstm_kernel<<<NBLK, NTHR, 0, stream>>>(X, ts, emb_pos, emb_team, Wfrag,
                                           Wall_b, Uall_b, Wd_b,
                                           lin_w, lin_b, nodes);
    sage_kernel<<<B_, 256, 0, stream>>>(nodes, edge, s1l, s1lb, s1r,
                                        s2l, s2lb, s2r, ow, ob, (float*)d_out);
}

// Round 6
// 296.434 us; speedup vs baseline: 2.3565x; 1.4016x over previous
//
#include <hip/hip_runtime.h>
#include <math.h>

#define B_    64
#define W_    128
#define N_    40
#define FIN   66
#define HID   100
#define NEWD  71
#define MSEQ  10
#define NBLK  256
#define NTHR  1024  // 16 waves: 13 compute + 3 staging
#define E_    240

#define NGU   150   // gate units: 25 tiles * 6 kc
#define NDU   100   // decay-mini units: 25 tiles * 4 kc (rows duplicated x4)
#define NU    250

// hx row: 2 parity regions of 192 cols ([0..99]=h [100..170]=xe [171]=1 [172..191]=0)
#define HROW  392
#define CROW  264   // cx row: 2 parity regions of 128 ([0..99]=c [100]=1 [101..127]=0)
#define ROWH(m) ((m)*HROW + (((m)>>3)<<3))
#define ROWC(m) ((m)*CROW + (((m)>>3)<<3))
#define HXSZ  (15*HROW + 8 + HROW)   // 6280
#define CXSZ  (15*CROW + 8 + CROW)   // 4232

typedef float    f32x4 __attribute__((ext_vector_type(4)));
typedef _Float16 f16x4 __attribute__((ext_vector_type(4)));
typedef _Float16 f16x8 __attribute__((ext_vector_type(8)));

__device__ __forceinline__ float sig_(float x) {
    return __builtin_amdgcn_rcpf(1.0f + __expf(-x));
}
__device__ __forceinline__ float tanh_(float x) {
    return fmaf(2.0f, __builtin_amdgcn_rcpf(1.0f + __expf(-2.0f * x)), -1.0f);
}

// lgkm-only barrier: LDS visibility without draining global prefetch (vmcnt)
#define LBAR() do {                                            \
    asm volatile("s_waitcnt lgkmcnt(0)" ::: "memory");         \
    __builtin_amdgcn_s_barrier();                              \
    asm volatile("" ::: "memory");                             \
} while (0)

// ---------------------------------------------------------------------------
// Repack weights into f16 A-fragments for mfma_f32_16x16x32_f16.
// A-frag: lane l holds rows R=l&15, k=(l>>4)*8+e.
// GATE (u<150): rows interleaved R=4*unit+gate -> src row gate*100+unit.
//   k<100: Wall; 100..170: Uall; k==171: Wall_b+Uall_b (bias-as-input); else 0.
// DECAY-MINI (u>=150): row R -> Wd row 4T+(R>>2) (4x duplicated rows).
//   k<100: Wd; k==100: Wd_b; else 0.
// ---------------------------------------------------------------------------
__global__ void repack_kernel(const float* __restrict__ Wall_w,
                              const float* __restrict__ Uall_w,
                              const float* __restrict__ Wd_w,
                              const float* __restrict__ Wall_b,
                              const float* __restrict__ Uall_b,
                              const float* __restrict__ Wd_b,
                              _Float16* __restrict__ Wfrag)
{
    int idx = blockIdx.x * 256 + threadIdx.x;
    if (idx >= NU * 64) return;
    int u = idx >> 6, l = idx & 63;
    f16x8 v;
    #pragma unroll
    for (int e = 0; e < 8; ++e) {
        float wv = 0.0f;
        int k = ((l >> 4) << 3) + e;
        if (u < NGU) {
            int T = u / 6, j = u % 6;
            int R = T * 16 + (l & 15);
            int src = (R & 3) * 100 + (R >> 2);
            k += j * 32;
            if (k < 100)       wv = Wall_w[src * HID + k];
            else if (k < 171)  wv = Uall_w[src * NEWD + (k - 100)];
            else if (k == 171) wv = Wall_b[src] + Uall_b[src];
        } else {
            int du = u - NGU;
            int T = du >> 2, j = du & 3;
            int srcrow = 4 * T + ((l & 15) >> 2);
            k += j * 32;
            if (k < 100)       wv = Wd_w[srcrow * HID + k];
            else if (k == 100) wv = Wd_b[srcrow];
        }
        v[e] = (_Float16)wv;
    }
    *(f16x8*)(Wfrag + (size_t)idx * 8) = v;
}

// ---------------------------------------------------------------------------
// LSTM: 256 blocks x 1024 threads. ONE lgkm barrier per step.
// Waves 0..12 compute: slots tA=2wv, tB=min(2wv+1,24) (wave12 duplicates, benign).
//   Per step: read bh[6]/bc[4] from parity p, 20 MFMA (12 gate + 8 decay-mini),
//   sigmoid/tanh + c/h update fully in-register, write h/c f16 to parity p^1.
// Waves 13..15 staging: write xe(w+1)/ts(w+1) to parity p^1 from regs
//   preloaded one step earlier (global loads never drained: LBAR has no vmcnt).
// ---------------------------------------------------------------------------
__global__ __launch_bounds__(NTHR, 4)
void lstm_kernel(const float* __restrict__ X, const float* __restrict__ ts,
                 const float* __restrict__ emb_pos, const float* __restrict__ emb_team,
                 const _Float16* __restrict__ Wfrag,
                 const float* __restrict__ lin_w, const float* __restrict__ lin_b,
                 float* __restrict__ nodes)
{
    __shared__ __align__(16) _Float16 hx[HXSZ];
    __shared__ __align__(16) _Float16 cx[CXSZ];
    __shared__ float ts_s[2][16];

    const int t = threadIdx.x, l = t & 63, wv = t >> 6;
    const int uoff = l >> 4, m = l & 15;
    const int r0 = blockIdx.x * MSEQ;
    const bool comp = (wv < 13);

    // ---- zero LDS ----
    for (int i = t; i < HXSZ; i += NTHR) hx[i] = (_Float16)0.0f;
    for (int i = t; i < CXSZ; i += NTHR) cx[i] = (_Float16)0.0f;
    if (t < 32) ((float*)ts_s)[t] = 0.0f;

    // ---- compute-wave setup ----
    const int tA = 2 * wv;
    const int tB = (2 * wv + 1 < 25) ? (2 * wv + 1) : 24;
    const int uA = 4 * tA + uoff, uB = 4 * tB + uoff;
    f16x8 afA[6], afB[6], adA[4], adB[4];
    if (comp) {
        #pragma unroll
        for (int j = 0; j < 6; ++j) {
            afA[j] = *(const f16x8*)(Wfrag + ((size_t)(tA * 6 + j) * 64 + l) * 8);
            afB[j] = *(const f16x8*)(Wfrag + ((size_t)(tB * 6 + j) * 64 + l) * 8);
        }
        #pragma unroll
        for (int j = 0; j < 4; ++j) {
            adA[j] = *(const f16x8*)(Wfrag + ((size_t)(NGU + tA * 4 + j) * 64 + l) * 8);
            adB[j] = *(const f16x8*)(Wfrag + ((size_t)(NGU + tB * 4 + j) * 64 + l) * 8);
        }
    }
    float cregA = 0.f, cregB = 0.f;

    // ---- staging roles (waves 13..15) ----
    const float* xld = nullptr; int xm = 0, xp = 0;
    const float* xcat = nullptr; int me = 0;
    const float* tsp = nullptr; int mt = 0;
    {
        int s = t - 832;
        if (s >= 0 && s < 160) {
            xm = s >> 4; xp = s & 15;
            int r = r0 + xm, b = r / N_, n = r % N_;
            xld = X + ((size_t)b * W_ * N_ + n) * FIN + 4 * xp;
        } else if (s >= 160 && s < 170) {
            me = s - 160;
            int r = r0 + me, b = r / N_, n = r % N_;
            xcat = X + ((size_t)b * W_ * N_ + n) * FIN;
        } else if (s >= 170 && s < 180) {
            mt = s - 170;
            int r = r0 + mt, b = r / N_, n = r % N_;
            tsp = ts + (size_t)b * W_ * N_ + n;
        }
    }
    __syncthreads();

    // ---- constant-1 bias inputs (both parities) ----
    if (t < 32) {
        int r = t & 15, p = t >> 4;
        hx[ROWH(r) + p * 192 + 171] = (_Float16)1.0f;
        cx[ROWC(r) + p * 128 + 100] = (_Float16)1.0f;
    }
    // ---- stage xe(0)/ts(0) into parity 0 ----
    if (xld) {
        float2 a = *(const float2*)xld;
        float2 b2 = *(const float2*)(xld + 2);
        f16x4 v = {(_Float16)a.x, (_Float16)a.y, (_Float16)b2.x, (_Float16)b2.y};
        *(f16x4*)&hx[ROWH(xm) + 100 + 4 * xp] = v;
    }
    if (xcat) {
        float c0f = xcat[64], c1f = xcat[65];
        int ip = (int)c0f, itm = (int)c1f;
        int sp = ip > 0 ? ip - 1 : 0;   float fp  = ip > 0 ? 1.f : 0.f;
        int st = itm > 0 ? itm - 1 : 0; float ft_ = itm > 0 ? 1.f : 0.f;
        #pragma unroll
        for (int q = 0; q < 4; ++q) hx[ROWH(me) + 164 + q] = (_Float16)(emb_pos[sp * 4 + q] * fp);
        #pragma unroll
        for (int q = 0; q < 3; ++q) hx[ROWH(me) + 168 + q] = (_Float16)(emb_team[st * 3 + q] * ft_);
    }
    if (tsp) ts_s[0][mt] = tsp[0];

    // ---- preload regs for step 1 ----
    float2 pa = {0.f, 0.f}, pb = {0.f, 0.f};
    float pc0 = 0.f, pc1 = 0.f, ptv = 0.f;
    {
        const size_t off1 = (size_t)N_ * FIN;
        if (xld)  { pa = *(const float2*)(xld + off1); pb = *(const float2*)(xld + off1 + 2); }
        if (xcat) { pc0 = xcat[off1 + 64]; pc1 = xcat[off1 + 65]; }
        if (tsp)  ptv = tsp[(size_t)N_];
    }
    __syncthreads();

    const int rowhm = ROWH(m) + (uoff << 3);   // B-read base (k-offset folded)
    const int rowcm = ROWC(m) + (uoff << 3);
    const int rowhw = ROWH(m);                 // h/c write base
    const int rowcw = ROWC(m);

    // ---- main loop: ONE barrier per step ----
    for (int w = 0; w < W_; ++w) {
        const int p = w & 1, np = p ^ 1;
        if (comp) {
            const int hb = rowhm + p * 192;
            f16x8 bh0 = *(const f16x8*)&hx[hb];
            f16x8 bh1 = *(const f16x8*)&hx[hb + 32];
            f16x8 bh2 = *(const f16x8*)&hx[hb + 64];
            f16x8 bh3 = *(const f16x8*)&hx[hb + 96];
            f16x8 bh4 = *(const f16x8*)&hx[hb + 128];
            f16x8 bh5 = *(const f16x8*)&hx[hb + 160];
            f32x4 aA = {0.f, 0.f, 0.f, 0.f}, aB = {0.f, 0.f, 0.f, 0.f};
            aA = __builtin_amdgcn_mfma_f32_16x16x32_f16(afA[0], bh0, aA, 0, 0, 0);
            aB = __builtin_amdgcn_mfma_f32_16x16x32_f16(afB[0], bh0, aB, 0, 0, 0);
            aA = __builtin_amdgcn_mfma_f32_16x16x32_f16(afA[1], bh1, aA, 0, 0, 0);
            aB = __builtin_amdgcn_mfma_f32_16x16x32_f16(afB[1], bh1, aB, 0, 0, 0);
            aA = __builtin_amdgcn_mfma_f32_16x16x32_f16(afA[2], bh2, aA, 0, 0, 0);
            aB = __builtin_amdgcn_mfma_f32_16x16x32_f16(afB[2], bh2, aB, 0, 0, 0);
            aA = __builtin_amdgcn_mfma_f32_16x16x32_f16(afA[3], bh3, aA, 0, 0, 0);
            aB = __builtin_amdgcn_mfma_f32_16x16x32_f16(afB[3], bh3, aB, 0, 0, 0);
            aA = __builtin_amdgcn_mfma_f32_16x16x32_f16(afA[4], bh4, aA, 0, 0, 0);
            aB = __builtin_amdgcn_mfma_f32_16x16x32_f16(afB[4], bh4, aB, 0, 0, 0);
            aA = __builtin_amdgcn_mfma_f32_16x16x32_f16(afA[5], bh5, aA, 0, 0, 0);
            aB = __builtin_amdgcn_mfma_f32_16x16x32_f16(afB[5], bh5, aB, 0, 0, 0);

            const int cb = rowcm + p * 128;
            f16x8 bc0 = *(const f16x8*)&cx[cb];
            f16x8 bc1 = *(const f16x8*)&cx[cb + 32];
            f16x8 bc2 = *(const f16x8*)&cx[cb + 64];
            f16x8 bc3 = *(const f16x8*)&cx[cb + 96];
            f32x4 dA = {0.f, 0.f, 0.f, 0.f}, dB = {0.f, 0.f, 0.f, 0.f};
            dA = __builtin_amdgcn_mfma_f32_16x16x32_f16(adA[0], bc0, dA, 0, 0, 0);
            dB = __builtin_amdgcn_mfma_f32_16x16x32_f16(adB[0], bc0, dB, 0, 0, 0);
            dA = __builtin_amdgcn_mfma_f32_16x16x32_f16(adA[1], bc1, dA, 0, 0, 0);
            dB = __builtin_amdgcn_mfma_f32_16x16x32_f16(adB[1], bc1, dB, 0, 0, 0);
            dA = __builtin_amdgcn_mfma_f32_16x16x32_f16(adA[2], bc2, dA, 0, 0, 0);
            dB = __builtin_amdgcn_mfma_f32_16x16x32_f16(adB[2], bc2, dB, 0, 0, 0);
            dA = __builtin_amdgcn_mfma_f32_16x16x32_f16(adA[3], bc3, dA, 0, 0, 0);
            dB = __builtin_amdgcn_mfma_f32_16x16x32_f16(adB[3], bc3, dB, 0, 0, 0);

            if (m < MSEQ) {
                float tsv = ts_s[p][m];
                float e1 = tsv - 1.0f;
                float cs1A = tanh_(dA[0]);
                float cnA = sig_(aA[0]) * fmaf(cs1A, e1, cregA) + sig_(aA[1]) * sig_(aA[3]);
                cregA = cnA;
                hx[rowhw + np * 192 + uA] = (_Float16)(sig_(aA[2]) * tanh_(cnA));
                cx[rowcw + np * 128 + uA] = (_Float16)cnA;
                float cs1B = tanh_(dB[0]);
                float cnB = sig_(aB[0]) * fmaf(cs1B, e1, cregB) + sig_(aB[1]) * sig_(aB[3]);
                cregB = cnB;
                hx[rowhw + np * 192 + uB] = (_Float16)(sig_(aB[2]) * tanh_(cnB));
                cx[rowcw + np * 128 + uB] = (_Float16)cnB;
            }
        } else {
            if (w + 1 < W_) {
                if (xld) {
                    f16x4 v = {(_Float16)pa.x, (_Float16)pa.y, (_Float16)pb.x, (_Float16)pb.y};
                    *(f16x4*)&hx[ROWH(xm) + np * 192 + 100 + 4 * xp] = v;
                }
                if (xcat) {
                    int ip = (int)pc0, itm = (int)pc1;
                    int sp = ip > 0 ? ip - 1 : 0;   float fp  = ip > 0 ? 1.f : 0.f;
                    int st = itm > 0 ? itm - 1 : 0; float ft_ = itm > 0 ? 1.f : 0.f;
                    #pragma unroll
                    for (int q = 0; q < 4; ++q) hx[ROWH(me) + np * 192 + 164 + q] = (_Float16)(emb_pos[sp * 4 + q] * fp);
                    #pragma unroll
                    for (int q = 0; q < 3; ++q) hx[ROWH(me) + np * 192 + 168 + q] = (_Float16)(emb_team[st * 3 + q] * ft_);
                }
                if (tsp) ts_s[np][mt] = ptv;
                if (w + 2 < W_) {
                    const size_t off = (size_t)(w + 2) * (N_ * FIN);
                    if (xld)  { pa = *(const float2*)(xld + off); pb = *(const float2*)(xld + off + 2); }
                    if (xcat) { pc0 = xcat[off + 64]; pc1 = xcat[off + 65]; }
                    if (tsp)  ptv = tsp[(size_t)(w + 2) * N_];
                }
            }
        }
        LBAR();
    }

    // ---- lin head: final h is in parity 0 (written at w=127 -> np=0) ----
    if (t < HID * MSEQ) {
        const int i = t / MSEQ, mm = t % MSEQ;
        const float* lr = lin_w + (size_t)i * HID;
        float acc2 = lin_b[i];
        for (int k = 0; k < HID; ++k)
            acc2 = fmaf(lr[k], (float)hx[ROWH(mm) + k], acc2);
        nodes[(size_t)(r0 + mm) * HID + i] = fmaxf(acc2, 0.0f);
    }
}

// ---------------------------------------------------------------------------
// Kernel B: per-batch GraphSAGE x2 + output head, all in LDS. (unchanged)
// ---------------------------------------------------------------------------
__global__ __launch_bounds__(256, 1)
void sage_kernel(const float* __restrict__ nodes, const int* __restrict__ edge,
                 const float* __restrict__ s1l, const float* __restrict__ s1lb,
                 const float* __restrict__ s1r,
                 const float* __restrict__ s2l, const float* __restrict__ s2lb,
                 const float* __restrict__ s2r,
                 const float* __restrict__ ow,  const float* __restrict__ ob,
                 float* __restrict__ out)
{
    __shared__ float nd[N_ * HID];
    __shared__ float agg[N_ * HID];
    __shared__ float g1[N_ * 64];
    __shared__ float agg2[N_ * 64];
    __shared__ float g2[N_ * 32];
    __shared__ float deg[N_];
    __shared__ float invdeg[N_];

    const int t = threadIdx.x;
    const int b = blockIdx.x;
    const int* esrc = edge;
    const int* edst = edge + E_;

    for (int i = t; i < N_ * HID; i += 256) {
        nd[i]  = nodes[(size_t)b * N_ * HID + i];
        agg[i] = 0.0f;
    }
    for (int i = t; i < N_; i += 256) deg[i] = 0.0f;
    __syncthreads();

    if (t < E_) atomicAdd(&deg[edst[t]], 1.0f);
    for (int i = t; i < E_ * HID; i += 256) {
        int e = i / HID, k = i % HID;
        atomicAdd(&agg[edst[e] * HID + k], nd[esrc[e] * HID + k]);
    }
    __syncthreads();
    for (int i = t; i < N_; i += 256) invdeg[i] = 1.0f / fmaxf(deg[i], 1.0f);
    __syncthreads();

    for (int idx = t; idx < N_ * 64; idx += 256) {
        int n = idx / 64, i = idx % 64;
        const float* lr = s1l + (size_t)i * HID;
        const float* rr = s1r + (size_t)i * HID;
        float id = invdeg[n];
        float acc = s1lb[i];
        for (int k = 0; k < HID; ++k)
            acc += lr[k] * (agg[n * HID + k] * id) + rr[k] * nd[n * HID + k];
        g1[idx] = fmaxf(acc, 0.0f);
    }
    __syncthreads();
    for (int i = t; i < N_ * 64; i += 256) agg2[i] = 0.0f;
    __syncthreads();
    for (int i = t; i < E_ * 64; i += 256) {
        int e = i / 64, k = i % 64;
        atomicAdd(&agg2[edst[e] * 64 + k], g1[esrc[e] * 64 + k]);
    }
    __syncthreads();

    for (int idx = t; idx < N_ * 32; idx += 256) {
        int n = idx / 32, i = idx % 32;
        const float* lr = s2l + (size_t)i * 64;
        const float* rr = s2r + (size_t)i * 64;
        float id = invdeg[n];
        float acc = s2lb[i];
        for (int k = 0; k < 64; ++k)
            acc += lr[k] * (agg2[n * 64 + k] * id) + rr[k] * g1[n * 64 + k];
        g2[idx] = fmaxf(acc, 0.0f);
    }
    __syncthreads();

    for (int idx = t; idx < N_ * 2; idx += 256) {
        int n = idx / 2, c = idx % 2;
        const float* wr = ow + (size_t)c * 32;
        float acc = ob[c];
        for (int k = 0; k < 32; ++k) acc += wr[k] * g2[n * 32 + k];
        out[((size_t)b * N_ + n) * 2 + c] = fmaxf(acc, 0.0f);
    }
}

extern "C" void kernel_launch(void* const* d_in, const int* in_sizes, int n_in,
                              void* d_out, int out_size, void* d_ws, size_t ws_size,
                              hipStream_t stream) {
    const float* X        = (const float*)d_in[0];
    const float* ts       = (const float*)d_in[1];
    const int*   edge     = (const int*)  d_in[2];
    const float* emb_pos  = (const float*)d_in[3];
    const float* emb_team = (const float*)d_in[4];
    const float* Wall_w   = (const float*)d_in[5];
    const float* Wall_b   = (const float*)d_in[6];
    const float* Uall_w   = (const float*)d_in[7];
    const float* Uall_b   = (const float*)d_in[8];
    const float* Wd_w     = (const float*)d_in[9];
    const float* Wd_b     = (const float*)d_in[10];
    const float* lin_w    = (const float*)d_in[11];
    const float* lin_b    = (const float*)d_in[12];
    const float* s1l      = (const float*)d_in[13];
    const float* s1lb     = (const float*)d_in[14];
    const float* s1r      = (const float*)d_in[15];
    const float* s2l      = (const float*)d_in[16];
    const float* s2lb     = (const float*)d_in[17];
    const float* s2r      = (const float*)d_in[18];
    const float* ow       = (const float*)d_in[19];
    const float* ob       = (const float*)d_in[20];

    float*     nodes = (float*)d_ws;                              // 1,024,000 B
    _Float16*  Wfrag = (_Float16*)((char*)d_ws + 1024000);        // 250*64*8*2 = 256,000 B

    repack_kernel<<<(NU * 64 + 255) / 256, 256, 0, stream>>>(Wall_w, Uall_w, Wd_w,
                                                             Wall_b, Uall_b, Wd_b, Wfrag);

    lstm_kernel<<<NBLK, NTHR, 0, stream>>>(X, ts, emb_pos, emb_team, Wfrag,
                                           lin_w, lin_b, nodes);
    sage_kernel<<<B_, 256, 0, stream>>>(nodes, edge, s1l, s1lb, s1r,
                                        s2l, s2lb, s2r, ow, ob, (float*)d_out);
}